// Round 10
// baseline (206.925 us; speedup 1.0000x reference)
//
#include <hip/hip_runtime.h>
#include <math.h>

// NoisyTopkRouter: x[T,2048] @ {Wg,Wn}[8,2048]^T -> logits[T,8] each,
// noisy = noise * softplus(noisy_pre) + gate; top-2 -> softmax -> scatter.
// T = 32768, D = 2048, E = 8, k = 2.
//
// R10: consolidation. R9's 3-kernel pipeline had ~6-9 us of structural
// overhead (transpose launch, finalize launch + cold 4 MB re-read).
// Now: ONE kernel + 2 KB memset.
//  - finalize fused via split-K flag protocol (threadfence + atomicAdd,
//    second arriver runs the epilogue on L2-hot partials).
//  - W scalar-loaded directly from Wg/Wn (wave-uniform -> s_load), no WT.
//  - DEPTH=5 LDS ring (40960 B = exactly 4 blocks/CU), consume-then-stage:
//    stage(c+3) after barrier(c) -> 3 chunks in flight, race-free with one
//    extra barrier of margin vs R9.
// Carried over validated: global_load_lds staging, XOR-pre-swizzled source
// + swizzled ds_read_b128 (conflict-free), counted vmcnt (never 0 in loop),
// acc[16]/lane, lane=token consume layout.

#define RD 2048
#define RE 8
#define NE16 16               // stacked experts: 0..7 = gate, 8..15 = noise
#define TOKB 64               // tokens per block (lane = token)
#define CH 32                 // d's per chunk (8 KB per chunk)
#define KSL 2                 // K-slices (blocks per token tile)
#define KLEN (RD / KSL)       // 1024 d's per block
#define NCH (KLEN / CH)       // 32 chunks
#define NW 4                  // waves per block
#define DEPTH 5               // LDS ring depth (40 KB -> 4 blocks/CU exactly)
#define CHF (TOKB * CH)       // floats per ring slot (2048)

#define AS1 __attribute__((address_space(1)))
#define AS3 __attribute__((address_space(3)))

#define WAITVM(N) asm volatile("s_waitcnt vmcnt(" #N ")" ::: "memory")

__device__ __forceinline__ void gload_lds16(const float* g, float* l) {
    // HBM -> LDS DMA, 16 B per lane; LDS dest is wave-uniform base + lane*16.
    __builtin_amdgcn_global_load_lds((const AS1 unsigned int*)g,
                                     (AS3 unsigned int*)l, 16, 0, 0);
}

__global__ __launch_bounds__(256) void router_fused_kernel(
    const float* __restrict__ x,
    const float* __restrict__ Wg,
    const float* __restrict__ bg,
    const float* __restrict__ Wn,
    const float* __restrict__ bn,
    const float* __restrict__ noise,
    float* __restrict__ pws,          // [KSL][T][16] partial sums (d_ws)
    int* __restrict__ flags,          // [T/TOKB], memset to 0 each call
    float* __restrict__ out_router,
    float* __restrict__ out_experts,
    int T)
{
    __shared__ float xb[DEPTH][CHF];   // 40960 B exactly; overlaid later

    const int tid = threadIdx.x;
    const int w = tid >> 6;              // wave 0..3 -> 8-d sub-range of chunk
    const int l = tid & 63;              // lane = token within tile
    const int NTB = T / TOKB;
    const int bt = blockIdx.x % NTB;     // token tile
    const int kslice = blockIdx.x / NTB; // K-slice
    const int tokBase = bt * TOKB;
    const int kbase = kslice * KLEN;

    float acc[NE16];
#pragma unroll
    for (int e = 0; e < NE16; ++e) acc[e] = 0.f;

    // Staging geometry (per chunk): 8 x 1 KB DMA insts; inst i = w*2+s
    // covers token rows i*8 .. i*8+7 (32-float rows, 8 16B-segs each).
    // lane -> row t = i*8 + (l>>3) (so t&7 == l>>3), phys seg p = l&7;
    // GLOBAL source seg is XOR-pre-swizzled (p ^ (t&7)): LDS[t][s] holds
    // x[t][s ^ (t&7)], so the consume read LDS[l][q ^ (l&7)] = x[l][q]
    // is bank-conflict-free while the LDS dest stays linear.
    const size_t laneoff = (size_t)(l >> 3) * RD + ((((l & 7) ^ (l >> 3))) << 2);
    const float* p0 = x + (size_t)(tokBase + (w * 2 + 0) * 8) * RD + kbase + laneoff;
    const float* p1 = x + (size_t)(tokBase + (w * 2 + 1) * 8) * RD + kbase + laneoff;
    float* d0 = &xb[0][(w * 2 + 0) * 256];
    float* d1 = &xb[0][(w * 2 + 1) * 256];

    // prologue: stage chunks 0,1,2 (6 insts outstanding per wave)
    gload_lds16(p0 + 0 * CH, d0 + 0 * CHF);
    gload_lds16(p1 + 0 * CH, d1 + 0 * CHF);
    gload_lds16(p0 + 1 * CH, d0 + 1 * CHF);
    gload_lds16(p1 + 1 * CH, d1 + 1 * CHF);
    gload_lds16(p0 + 2 * CH, d0 + 2 * CHF);
    gload_lds16(p1 + 2 * CH, d1 + 2 * CHF);

    int cb = 0;            // ring slot holding chunk c
    int rb = 3;            // ring slot for stage of chunk c+3

#pragma unroll 1
    for (int c = 0; c < NCH; ++c) {
        // counted wait: chunk c landed; c+1, c+2 stay in flight
        if (c <= NCH - 3)      { WAITVM(4); }
        else if (c == NCH - 2) { WAITVM(2); }
        else                   { WAITVM(0); }
        __builtin_amdgcn_s_barrier();       // all waves' chunk-c DMA landed
        __builtin_amdgcn_sched_barrier(0);  // no hoisting across

        // consume chunk c: wave w covers logical segs q = w*2, w*2+1
        // (d = kbase + c*32 + q*4 + ii). W base wave-uniform -> s_load.
        const int woff = __builtin_amdgcn_readfirstlane(kbase + c * CH + w * 8);
        const float* __restrict__ wgb = Wg + woff;
        const float* __restrict__ wnb = Wn + woff;
#pragma unroll
        for (int r = 0; r < 2; ++r) {
            const int q = w * 2 + r;
            const float4 xq = *reinterpret_cast<const float4*>(
                &xb[cb][l * CH + ((q ^ (l & 7)) << 2)]);
            const float xs[4] = {xq.x, xq.y, xq.z, xq.w};
#pragma unroll
            for (int e = 0; e < RE; ++e) {
                const float4 a = *reinterpret_cast<const float4*>(wgb + e * RD + r * 4);
                const float4 b = *reinterpret_cast<const float4*>(wnb + e * RD + r * 4);
                acc[e]     = fmaf(xs[0], a.x, acc[e]);
                acc[e]     = fmaf(xs[1], a.y, acc[e]);
                acc[e]     = fmaf(xs[2], a.z, acc[e]);
                acc[e]     = fmaf(xs[3], a.w, acc[e]);
                acc[8 + e] = fmaf(xs[0], b.x, acc[8 + e]);
                acc[8 + e] = fmaf(xs[1], b.y, acc[8 + e]);
                acc[8 + e] = fmaf(xs[2], b.z, acc[8 + e]);
                acc[8 + e] = fmaf(xs[3], b.w, acc[8 + e]);
            }
        }

        // stage chunk c+3 AFTER barrier(c): its slot last held chunk c-2,
        // whose reads completed before barrier(c-1) in every wave. Safe.
        if (c + 3 < NCH) {
            gload_lds16(p0 + (c + 3) * CH, d0 + rb * CHF);
            gload_lds16(p1 + (c + 3) * CH, d1 + rb * CHF);
        }
        if (++rb == DEPTH) rb = 0;
        if (++cb == DEPTH) cb = 0;
    }

    __syncthreads();   // everything retired; safe to overlay xb

    // ---- cross-wave reduction overlay (needs 4096 floats of xb) ----
    float* red = &xb[0][0];
    {
        const int roff = (w * TOKB + l) * NE16;
        *reinterpret_cast<float4*>(&red[roff + 0])  = make_float4(acc[0], acc[1], acc[2], acc[3]);
        *reinterpret_cast<float4*>(&red[roff + 4])  = make_float4(acc[4], acc[5], acc[6], acc[7]);
        *reinterpret_cast<float4*>(&red[roff + 8])  = make_float4(acc[8], acc[9], acc[10], acc[11]);
        *reinterpret_cast<float4*>(&red[roff + 12]) = make_float4(acc[12], acc[13], acc[14], acc[15]);
    }
    __syncthreads();

    // 256 threads: (token, quad) -> sum 4 wave partials, one float4 out
    {
        const int tok = tid >> 2;
        const int q4 = tid & 3;
        float4 s = make_float4(0.f, 0.f, 0.f, 0.f);
#pragma unroll
        for (int wv = 0; wv < NW; ++wv) {
            const float4 a = *reinterpret_cast<const float4*>(
                &red[(wv * TOKB + tok) * NE16 + q4 * 4]);
            s.x += a.x; s.y += a.y; s.z += a.z; s.w += a.w;
        }
        float* dst = pws + ((size_t)kslice * T + tokBase + tok) * NE16 + q4 * 4;
        *reinterpret_cast<float4*>(dst) = s;
    }

    // ---- fused finalize: second K-slice block to finish runs epilogue ----
    __threadfence();                 // release: partials visible device-wide
    __syncthreads();
    int* amF = (int*)&xb[4][0];      // overlay, past the 4096-float red area
    if (tid == 0) *amF = atomicAdd(flags + bt, 1);
    __syncthreads();
    if (*amF != 1) return;           // first arriver exits
    __threadfence();                 // acquire: see the other block's partials

    if (tid < TOKB) {
        const int tok = tokBase + tid;
        const float* pp0 = pws + (size_t)tok * NE16;
        const float* pp1 = pws + ((size_t)T + tok) * NE16;

        float g[RE], nn[RE];
#pragma unroll
        for (int e = 0; e < RE; ++e) {
            g[e]  = pp0[e] + pp1[e] + bg[e];
            nn[e] = pp0[8 + e] + pp1[8 + e] + bn[e];
        }

        const float4* nzp = reinterpret_cast<const float4*>(noise + (size_t)tok * RE);
        const float4 nz0 = nzp[0];
        const float4 nz1 = nzp[1];
        const float nzv[RE] = {nz0.x, nz0.y, nz0.z, nz0.w,
                               nz1.x, nz1.y, nz1.z, nz1.w};

        float v[RE];
#pragma unroll
        for (int e = 0; e < RE; ++e) {
            const float p = nn[e];
            // stable softplus: max(p,0) + log1p(exp(-|p|))
            const float sp = fmaxf(p, 0.f) + log1pf(expf(-fabsf(p)));
            v[e] = fmaf(nzv[e], sp, g[e]);
        }

        // top-2 of 8; strict '>' keeps the lowest index on ties, matching
        // jax.lax.top_k / torch.topk ordering.
        int i1 = 0; float m1 = v[0];
#pragma unroll
        for (int e = 1; e < RE; ++e)
            if (v[e] > m1) { m1 = v[e]; i1 = e; }
        int i2 = -1; float m2 = -INFINITY;
#pragma unroll
        for (int e = 0; e < RE; ++e)
            if (e != i1 && v[e] > m2) { m2 = v[e]; i2 = e; }

        const float e2 = expf(m2 - m1);
        const float inv = 1.f / (1.f + e2);
        const float p1s = inv;
        const float p2s = e2 * inv;

        float r[RE];
#pragma unroll
        for (int e = 0; e < RE; ++e)
            r[e] = (e == i1) ? p1s : ((e == i2) ? p2s : 0.f);

        float4* orow = reinterpret_cast<float4*>(out_router + (size_t)tok * RE);
        orow[0] = make_float4(r[0], r[1], r[2], r[3]);
        orow[1] = make_float4(r[4], r[5], r[6], r[7]);

        float2* erow = reinterpret_cast<float2*>(out_experts + (size_t)tok * 2);
        *erow = make_float2((float)i1, (float)i2);
    }
}

extern "C" void kernel_launch(void* const* d_in, const int* in_sizes, int n_in,
                              void* d_out, int out_size, void* d_ws, size_t ws_size,
                              hipStream_t stream) {
    const float* x   = (const float*)d_in[0];
    const float* Wg  = (const float*)d_in[1];
    const float* bg  = (const float*)d_in[2];
    const float* Wn  = (const float*)d_in[3];
    const float* bn  = (const float*)d_in[4];
    const float* nz  = (const float*)d_in[5];
    const int T = in_sizes[0] / RD;              // 32768
    const int NTB = T / TOKB;                    // 512

    float* pws  = (float*)d_ws;                  // KSL*T*16 floats = 4 MB
    int* flags  = (int*)(pws + (size_t)KSL * T * NE16);  // 2 KB

    float* out_router  = (float*)d_out;                // T*8 floats
    float* out_experts = out_router + (size_t)T * RE;  // T*2 floats (as f32)

    hipMemsetAsync(flags, 0, NTB * sizeof(int), stream);

    hipLaunchKernelGGL(router_fused_kernel, dim3(NTB * KSL), dim3(256), 0,
                       stream, x, Wg, bg, Wn, bn, nz, pws, flags,
                       out_router, out_experts, T);
}

// Round 11
// 180.306 us; speedup vs baseline: 1.1476x; 1.1476x over previous
//
#include <hip/hip_runtime.h>
#include <math.h>

// NoisyTopkRouter: x[T,2048] @ {Wg,Wn}[8,2048]^T -> logits[T,8] each,
// noisy = noise * softplus(noisy_pre) + gate; top-2 -> softmax -> scatter.
// T = 32768, D = 2048, E = 8, k = 2.
//
// R11 = R9 (proven 60.8 us) + fused finalize ONLY.
// R10's 3.4x regression root cause: consume-then-stage reorder put the 16
// uniform W vector loads (which count in vmcnt!) BEFORE the staged DMA in
// issue order, so WAITVM(4) was only satisfiable once the PREVIOUS
// iteration's DMA landed -> full HBM latency stall per chunk. Reverted to
// R9's stage(c+2) -> WAITVM(4) -> barrier -> consume(c) order and the
// contiguous WT[d][16] scalar-path weights.
// Kept from R10: split-K flag protocol (threadfence + atomicAdd; the
// second-arriving K-slice block runs the epilogue on L2-hot partials),
// killing the finalize launch + 4 MB cold re-read.

#define RD 2048
#define RE 8
#define NE16 16               // stacked experts: 0..7 = gate, 8..15 = noise
#define TOKB 64               // tokens per block (lane = token)
#define CH 32                 // d's per chunk (8 KB per chunk)
#define KSL 2                 // K-slices (blocks per token tile)
#define KLEN (RD / KSL)       // 1024 d's per block
#define NCH (KLEN / CH)       // 32 chunks
#define NW 4                  // waves per block
#define DEPTH 4               // LDS ring depth
#define CHF (TOKB * CH)       // floats per ring slot (2048)

#define AS1 __attribute__((address_space(1)))
#define AS3 __attribute__((address_space(3)))

#define WAITVM(N) asm volatile("s_waitcnt vmcnt(" #N ")" ::: "memory")

__device__ __forceinline__ void gload_lds16(const float* g, float* l) {
    // HBM -> LDS DMA, 16 B per lane; LDS dest is wave-uniform base + lane*16.
    __builtin_amdgcn_global_load_lds((const AS1 unsigned int*)g,
                                     (AS3 unsigned int*)l, 16, 0, 0);
}

// ---- kernel 1: WT[d][e] = (e<8 ? Wg[e][d] : Wn[e-8][d]) ----
__global__ __launch_bounds__(256) void transpose_w_kernel(
    const float* __restrict__ Wg, const float* __restrict__ Wn,
    float* __restrict__ WT)
{
    const int idx = blockIdx.x * 256 + threadIdx.x;   // 0 .. 2048*16-1
    const int d = idx >> 4;
    const int e = idx & 15;
    WT[idx] = (e < 8) ? Wg[e * RD + d] : Wn[(e - 8) * RD + d];
}

// ---- kernel 2: main GEMV + fused epilogue ----
__global__ __launch_bounds__(256) void router_main_kernel(
    const float* __restrict__ x,
    const float* __restrict__ WT,     // [2048][16]
    const float* __restrict__ bg,
    const float* __restrict__ bn,
    const float* __restrict__ noise,
    float* __restrict__ pws,          // [KSL][T][16] partial sums (d_ws)
    int* __restrict__ flags,          // [T/TOKB], zeroed each call
    float* __restrict__ out_router,
    float* __restrict__ out_experts,
    int T)
{
    __shared__ float xb[DEPTH][CHF];   // 4 x 8 KB ring; overlaid later

    const int tid = threadIdx.x;
    const int w = tid >> 6;              // wave 0..3 -> 8-d sub-range of chunk
    const int l = tid & 63;              // lane = token within tile
    const int NTB = T / TOKB;
    const int bt = blockIdx.x % NTB;     // token tile
    const int kslice = blockIdx.x / NTB; // K-slice
    const int tokBase = bt * TOKB;
    const int kbase = kslice * KLEN;

    float acc[NE16];
#pragma unroll
    for (int e = 0; e < NE16; ++e) acc[e] = 0.f;

    // Staging geometry (per chunk): 8 x 1 KB DMA insts; inst i = w*2+s
    // covers token rows i*8 .. i*8+7 (32-float rows, 8 16B-segs each).
    // lane -> row t = i*8 + (l>>3) (so t&7 == l>>3), phys seg p = l&7;
    // GLOBAL source seg is XOR-pre-swizzled (p ^ (t&7)): LDS[t][s] holds
    // x[t][s ^ (t&7)], so the consume read LDS[l][q ^ (l&7)] = x[l][q]
    // while the LDS dest stays linear (global_load_lds requirement).
    const size_t laneoff = (size_t)(l >> 3) * RD + ((((l & 7) ^ (l >> 3))) << 2);
    const float* p0 = x + (size_t)(tokBase + (w * 2 + 0) * 8) * RD + kbase + laneoff;
    const float* p1 = x + (size_t)(tokBase + (w * 2 + 1) * 8) * RD + kbase + laneoff;
    float* d0base = &xb[0][(w * 2 + 0) * 256];
    float* d1base = &xb[0][(w * 2 + 1) * 256];

    // prologue: stage chunks 0 and 1 (4 insts outstanding per wave)
    gload_lds16(p0 + 0 * CH, d0base + 0 * CHF);
    gload_lds16(p1 + 0 * CH, d1base + 0 * CHF);
    gload_lds16(p0 + 1 * CH, d0base + 1 * CHF);
    gload_lds16(p1 + 1 * CH, d1base + 1 * CHF);

#pragma unroll 1
    for (int c = 0; c < NCH; ++c) {
        const int b = c & (DEPTH - 1);

        // stage chunk c+2 FIRST (R9 order!), then counted wait: the wait's
        // "all but newest 4" set then ends exactly at chunk c's DMA.
        if (c + 2 < NCH) {
            const int nb = (c + 2) & (DEPTH - 1);
            gload_lds16(p0 + (c + 2) * CH, d0base + nb * CHF);
            gload_lds16(p1 + (c + 2) * CH, d1base + nb * CHF);
            WAITVM(4);               // chunk c's 2 insts retired; c+1,c+2 fly
        } else if (c + 2 == NCH) {
            WAITVM(2);               // chunk c retired; c+1 still in flight
        } else {
            WAITVM(0);               // last chunk
        }
        __builtin_amdgcn_s_barrier();       // all waves' chunk-c DMA landed
        __builtin_amdgcn_sched_barrier(0);  // no hoisting across

        // consume chunk c: wave w covers logical segs q = w*2, w*2+1
        // (d = kbase + c*32 + q*4 + ii). WT base wave-uniform; contiguous
        // 512 B per chunk per wave -> scalar-cache friendly.
        const int wbase = __builtin_amdgcn_readfirstlane(
            (kbase + c * CH + w * 8) * NE16);
        const float* __restrict__ wt = WT + wbase;
#pragma unroll
        for (int r = 0; r < 2; ++r) {
            const int q = w * 2 + r;
            const float4 xq = *reinterpret_cast<const float4*>(
                &xb[b][l * CH + ((q ^ (l & 7)) << 2)]);
            const float xs[4] = {xq.x, xq.y, xq.z, xq.w};
#pragma unroll
            for (int ii = 0; ii < 4; ++ii) {
                const float* wrow = wt + (r * 4 + ii) * NE16;
#pragma unroll
                for (int e = 0; e < NE16; ++e)
                    acc[e] = fmaf(xs[ii], wrow[e], acc[e]);
            }
        }
        // ring depth 4 + per-iter barrier: stage(c+2) overwrites the slot
        // last holding chunk c-2, whose reads finished before barrier(c-1).
    }

    __syncthreads();   // everything retired; safe to overlay xb

    // ---- cross-wave reduction overlay (needs 4096 floats of xb) ----
    float* red = &xb[0][0];
    {
        const int roff = (w * TOKB + l) * NE16;
        *reinterpret_cast<float4*>(&red[roff + 0])  = make_float4(acc[0], acc[1], acc[2], acc[3]);
        *reinterpret_cast<float4*>(&red[roff + 4])  = make_float4(acc[4], acc[5], acc[6], acc[7]);
        *reinterpret_cast<float4*>(&red[roff + 8])  = make_float4(acc[8], acc[9], acc[10], acc[11]);
        *reinterpret_cast<float4*>(&red[roff + 12]) = make_float4(acc[12], acc[13], acc[14], acc[15]);
    }
    __syncthreads();

    // 256 threads: (token, quad) -> sum 4 wave partials, one float4 out
    {
        const int tok = tid >> 2;
        const int q4 = tid & 3;
        float4 s = make_float4(0.f, 0.f, 0.f, 0.f);
#pragma unroll
        for (int wv = 0; wv < NW; ++wv) {
            const float4 a = *reinterpret_cast<const float4*>(
                &red[(wv * TOKB + tok) * NE16 + q4 * 4]);
            s.x += a.x; s.y += a.y; s.z += a.z; s.w += a.w;
        }
        float* dst = pws + ((size_t)kslice * T + tokBase + tok) * NE16 + q4 * 4;
        *reinterpret_cast<float4*>(dst) = s;
    }

    // ---- fused finalize: second K-slice block to arrive runs epilogue ----
    __threadfence();                 // release: my partials visible
    __syncthreads();
    int* amF = (int*)&red[4096];     // overlay, past the reduction area
    if (tid == 0) *amF = atomicAdd(flags + bt, 1);
    __syncthreads();
    if (*amF != 1) return;           // first arriver exits
    __threadfence();                 // acquire: other block's partials visible

    if (tid < TOKB) {
        const int tok = tokBase + tid;
        const float* pp0 = pws + (size_t)tok * NE16;
        const float* pp1 = pws + ((size_t)T + tok) * NE16;

        float g[RE], nn[RE];
#pragma unroll
        for (int e = 0; e < RE; ++e) {
            g[e]  = pp0[e] + pp1[e] + bg[e];
            nn[e] = pp0[8 + e] + pp1[8 + e] + bn[e];
        }

        const float4* nzp = reinterpret_cast<const float4*>(noise + (size_t)tok * RE);
        const float4 nz0 = nzp[0];
        const float4 nz1 = nzp[1];
        const float nzv[RE] = {nz0.x, nz0.y, nz0.z, nz0.w,
                               nz1.x, nz1.y, nz1.z, nz1.w};

        float v[RE];
#pragma unroll
        for (int e = 0; e < RE; ++e) {
            const float p = nn[e];
            // stable softplus: max(p,0) + log1p(exp(-|p|))
            const float sp = fmaxf(p, 0.f) + log1pf(expf(-fabsf(p)));
            v[e] = fmaf(nzv[e], sp, g[e]);
        }

        // top-2 of 8; strict '>' keeps the lowest index on ties, matching
        // jax.lax.top_k / torch.topk ordering.
        int i1 = 0; float m1 = v[0];
#pragma unroll
        for (int e = 1; e < RE; ++e)
            if (v[e] > m1) { m1 = v[e]; i1 = e; }
        int i2 = -1; float m2 = -INFINITY;
#pragma unroll
        for (int e = 0; e < RE; ++e)
            if (e != i1 && v[e] > m2) { m2 = v[e]; i2 = e; }

        const float e2 = expf(m2 - m1);
        const float inv = 1.f / (1.f + e2);
        const float p1s = inv;
        const float p2s = e2 * inv;

        float r[RE];
#pragma unroll
        for (int e = 0; e < RE; ++e)
            r[e] = (e == i1) ? p1s : ((e == i2) ? p2s : 0.f);

        float4* orow = reinterpret_cast<float4*>(out_router + (size_t)tok * RE);
        orow[0] = make_float4(r[0], r[1], r[2], r[3]);
        orow[1] = make_float4(r[4], r[5], r[6], r[7]);

        float2* erow = reinterpret_cast<float2*>(out_experts + (size_t)tok * 2);
        *erow = make_float2((float)i1, (float)i2);
    }
}

extern "C" void kernel_launch(void* const* d_in, const int* in_sizes, int n_in,
                              void* d_out, int out_size, void* d_ws, size_t ws_size,
                              hipStream_t stream) {
    const float* x   = (const float*)d_in[0];
    const float* Wg  = (const float*)d_in[1];
    const float* bg  = (const float*)d_in[2];
    const float* Wn  = (const float*)d_in[3];
    const float* bn  = (const float*)d_in[4];
    const float* nz  = (const float*)d_in[5];
    const int T = in_sizes[0] / RD;              // 32768
    const int NTB = T / TOKB;                    // 512

    float* WT   = (float*)d_ws;                  // 128 KB
    float* pws  = WT + (size_t)RD * NE16;        // KSL*T*16 floats = 4 MB
    int* flags  = (int*)(pws + (size_t)KSL * T * NE16);  // 2 KB

    float* out_router  = (float*)d_out;                // T*8 floats
    float* out_experts = out_router + (size_t)T * RE;  // T*2 floats (as f32)

    hipMemsetAsync(flags, 0, NTB * sizeof(int), stream);

    hipLaunchKernelGGL(transpose_w_kernel, dim3((RD * NE16) / 256), dim3(256),
                       0, stream, Wg, Wn, WT);

    hipLaunchKernelGGL(router_main_kernel, dim3(NTB * KSL), dim3(256), 0,
                       stream, x, WT, bg, bn, nz, pws, flags,
                       out_router, out_experts, T);
}

// Round 12
// 64.773 us; speedup vs baseline: 3.1946x; 2.7837x over previous
//
#include <hip/hip_runtime.h>
#include <math.h>

// NoisyTopkRouter: x[T,2048] @ {Wg,Wn}[8,2048]^T -> logits[T,8] each,
// noisy = noise * softplus(noisy_pre) + gate; top-2 -> softmax -> scatter.
// T = 32768, D = 2048, E = 8, k = 2.
//
// R12 = R9 (proven 60.8 us) + W moved from the scalar-load path into the
// LDS ring. R9's residual stall: per-chunk W s_loads (512 B/wave) sit inside
// the barrier region -> K$-miss latency exposed on all 32 chunks. Now W is
// staged with the same global_load_lds pipeline as x (2 extra width-4 insts
// per wave per chunk; vmcnt stays uniformly counted: 4 ops/chunk, WAITVM(8)
// = 2 chunks in flight) and consumed via uniform-address ds_read_b128
// (broadcast, conflict-free, lgkmcnt path).
// Lesson from R10/R11 (both ~3-4x regressions): the epilogue/atomic protocol
// must NOT live in the counted-vmcnt kernel (it flips W loads onto the vmcnt
// path). Transpose + separate finalize kernels kept verbatim.

#define RD 2048
#define RE 8
#define NE16 16               // stacked experts: 0..7 = gate, 8..15 = noise
#define TOKB 64               // tokens per block (lane = token)
#define CH 32                 // d's per chunk (8 KB x + 2 KB W per chunk)
#define KSL 2                 // K-slices (blocks per token tile)
#define KLEN (RD / KSL)       // 1024 d's per block
#define NCH (KLEN / CH)       // 32 chunks
#define NW 4                  // waves per block
#define DEPTH 4               // LDS ring depth
#define CHF (TOKB * CH)       // floats per x ring slot (2048)
#define WCHF (CH * NE16)      // floats per W ring slot (512)

#define AS1 __attribute__((address_space(1)))
#define AS3 __attribute__((address_space(3)))

#define WAITVM(N) asm volatile("s_waitcnt vmcnt(" #N ")" ::: "memory")

__device__ __forceinline__ void gload_lds16(const float* g, float* l) {
    // HBM -> LDS DMA, 16 B per lane; LDS dest = wave-uniform base + lane*16.
    __builtin_amdgcn_global_load_lds((const AS1 unsigned int*)g,
                                     (AS3 unsigned int*)l, 16, 0, 0);
}
__device__ __forceinline__ void gload_lds4(const float* g, float* l) {
    // 4 B per lane; LDS dest = wave-uniform base + lane*4.
    __builtin_amdgcn_global_load_lds((const AS1 unsigned int*)g,
                                     (AS3 unsigned int*)l, 4, 0, 0);
}

// ---- kernel 1: WT[d][e] = (e<8 ? Wg[e][d] : Wn[e-8][d]) ----
__global__ __launch_bounds__(256) void transpose_w_kernel(
    const float* __restrict__ Wg, const float* __restrict__ Wn,
    float* __restrict__ WT)
{
    const int idx = blockIdx.x * 256 + threadIdx.x;   // 0 .. 2048*16-1
    const int d = idx >> 4;
    const int e = idx & 15;
    WT[idx] = (e < 8) ? Wg[e * RD + d] : Wn[(e - 8) * RD + d];
}

// ---- kernel 2: main GEMV, one K-slice per block, partials to d_ws ----
__global__ __launch_bounds__(256) void router_main_kernel(
    const float* __restrict__ x,
    const float* __restrict__ WT,     // [2048][16]
    float* __restrict__ pws,          // [KSL][T][16] partial sums
    int T)
{
    __shared__ float xb[DEPTH][CHF];   // 32 KB x ring
    __shared__ float wb[DEPTH][WCHF];  // 8 KB W ring  (total 40960 B)

    const int tid = threadIdx.x;
    const int w = tid >> 6;              // wave 0..3 -> 8-d sub-range of chunk
    const int l = tid & 63;              // lane = token within tile
    const int NTB = T / TOKB;
    const int bt = blockIdx.x % NTB;     // token tile
    const int kslice = blockIdx.x / NTB; // K-slice
    const int tokBase = bt * TOKB;
    const int kbase = kslice * KLEN;

    float acc[NE16];
#pragma unroll
    for (int e = 0; e < NE16; ++e) acc[e] = 0.f;

    // x staging (verbatim R9): 8 x 1 KB DMA per chunk; inst i = w*2+s covers
    // token rows i*8..i*8+7. lane -> row t = i*8 + (l>>3), phys seg p = l&7;
    // GLOBAL source seg is XOR-pre-swizzled (p ^ (t&7)) so the consume read
    // LDS[l][q ^ (l&7)] = x[l][q] is bank-free while LDS dest stays linear.
    const size_t laneoff = (size_t)(l >> 3) * RD + ((((l & 7) ^ (l >> 3))) << 2);
    const float* p0 = x + (size_t)(tokBase + (w * 2 + 0) * 8) * RD + kbase + laneoff;
    const float* p1 = x + (size_t)(tokBase + (w * 2 + 1) * 8) * RD + kbase + laneoff;
    float* d0base = &xb[0][(w * 2 + 0) * 256];
    float* d1base = &xb[0][(w * 2 + 1) * 256];

    // W staging: wave w's slice of chunk c = WT[(kbase+c*32+w*8)*16 .. +128)
    // (contiguous 512 B), staged as 2 width-4 insts of 256 B each.
    const float* wsrc0 = WT + (size_t)(kbase + w * 8) * NE16;   // + c*CH*NE16

    // prologue: stage chunks 0 and 1 (4 ops per chunk per wave)
#pragma unroll
    for (int cc = 0; cc < 2; ++cc) {
        gload_lds16(p0 + cc * CH, d0base + cc * CHF);
        gload_lds16(p1 + cc * CH, d1base + cc * CHF);
        const float* ws = wsrc0 + (size_t)cc * CH * NE16;
        gload_lds4(ws + l,      &wb[cc][w * 128]);
        gload_lds4(ws + 64 + l, &wb[cc][w * 128 + 64]);
    }

#pragma unroll 1
    for (int c = 0; c < NCH; ++c) {
        const int b = c & (DEPTH - 1);

        // stage chunk c+2 FIRST (R9 order), then counted wait:
        // 4 vmem ops/chunk/wave -> WAITVM(8) leaves c+1, c+2 in flight.
        if (c + 2 < NCH) {
            const int nb = (c + 2) & (DEPTH - 1);
            gload_lds16(p0 + (c + 2) * CH, d0base + nb * CHF);
            gload_lds16(p1 + (c + 2) * CH, d1base + nb * CHF);
            const float* ws = wsrc0 + (size_t)(c + 2) * CH * NE16;
            gload_lds4(ws + l,      &wb[nb][w * 128]);
            gload_lds4(ws + 64 + l, &wb[nb][w * 128 + 64]);
            WAITVM(8);               // chunk c's 4 insts retired
        } else if (c + 2 == NCH) {
            WAITVM(4);               // chunk c retired; c+1 still in flight
        } else {
            WAITVM(0);               // last chunk
        }
        __builtin_amdgcn_s_barrier();       // all waves' chunk-c DMA landed
        __builtin_amdgcn_sched_barrier(0);  // no hoisting across

        // consume chunk c: wave w covers logical segs q = w*2, w*2+1
        // (d = kbase + c*32 + q*4 + ii). W from LDS, uniform addr ->
        // broadcast ds_read_b128, conflict-free, latency pipelined by ring.
        const int wlb = w * 128;
#pragma unroll
        for (int r = 0; r < 2; ++r) {
            const int q = w * 2 + r;
            const float4 xq = *reinterpret_cast<const float4*>(
                &xb[b][l * CH + ((q ^ (l & 7)) << 2)]);
            const float xs[4] = {xq.x, xq.y, xq.z, xq.w};
#pragma unroll
            for (int ii = 0; ii < 4; ++ii) {
#pragma unroll
                for (int j = 0; j < 4; ++j) {
                    const float4 wq = *reinterpret_cast<const float4*>(
                        &wb[b][wlb + (r * 4 + ii) * NE16 + j * 4]);
                    acc[j * 4 + 0] = fmaf(xs[ii], wq.x, acc[j * 4 + 0]);
                    acc[j * 4 + 1] = fmaf(xs[ii], wq.y, acc[j * 4 + 1]);
                    acc[j * 4 + 2] = fmaf(xs[ii], wq.z, acc[j * 4 + 2]);
                    acc[j * 4 + 3] = fmaf(xs[ii], wq.w, acc[j * 4 + 3]);
                }
            }
        }
        // ring depth 4 + per-iter barrier: stage(c+2) overwrites the slot
        // last holding chunk c-2, whose reads finished before barrier(c-1).
    }

    __syncthreads();   // everything retired; safe to overlay xb

    // ---- cross-wave reduction overlay (needs 4096 floats of xb) ----
    float* red = &xb[0][0];
    {
        const int roff = (w * TOKB + l) * NE16;
        *reinterpret_cast<float4*>(&red[roff + 0])  = make_float4(acc[0], acc[1], acc[2], acc[3]);
        *reinterpret_cast<float4*>(&red[roff + 4])  = make_float4(acc[4], acc[5], acc[6], acc[7]);
        *reinterpret_cast<float4*>(&red[roff + 8])  = make_float4(acc[8], acc[9], acc[10], acc[11]);
        *reinterpret_cast<float4*>(&red[roff + 12]) = make_float4(acc[12], acc[13], acc[14], acc[15]);
    }
    __syncthreads();

    // 256 threads: (token, quad) -> sum 4 wave partials, one float4 out
    {
        const int tok = tid >> 2;
        const int q4 = tid & 3;
        float4 s = make_float4(0.f, 0.f, 0.f, 0.f);
#pragma unroll
        for (int wv = 0; wv < NW; ++wv) {
            const float4 a = *reinterpret_cast<const float4*>(
                &red[(wv * TOKB + tok) * NE16 + q4 * 4]);
            s.x += a.x; s.y += a.y; s.z += a.z; s.w += a.w;
        }
        float* dst = pws + ((size_t)kslice * T + tokBase + tok) * NE16 + q4 * 4;
        *reinterpret_cast<float4*>(dst) = s;
    }
}

// ---- kernel 3: combine K-slices + epilogue ----
__global__ __launch_bounds__(256) void router_finalize_kernel(
    const float* __restrict__ pws,
    const float* __restrict__ bg,
    const float* __restrict__ bn,
    const float* __restrict__ noise,
    float* __restrict__ out_router,
    float* __restrict__ out_experts,
    int T)
{
    const int tok = blockIdx.x * 256 + threadIdx.x;

    const float* pp0 = pws + (size_t)tok * NE16;
    const float* pp1 = pws + ((size_t)T + tok) * NE16;

    float g[RE], nn[RE];
#pragma unroll
    for (int e = 0; e < RE; ++e) {
        g[e]  = pp0[e] + pp1[e] + bg[e];
        nn[e] = pp0[8 + e] + pp1[8 + e] + bn[e];
    }

    const float4* nzp = reinterpret_cast<const float4*>(noise + (size_t)tok * RE);
    const float4 nz0 = nzp[0];
    const float4 nz1 = nzp[1];
    const float nzv[RE] = {nz0.x, nz0.y, nz0.z, nz0.w,
                           nz1.x, nz1.y, nz1.z, nz1.w};

    float v[RE];
#pragma unroll
    for (int e = 0; e < RE; ++e) {
        const float p = nn[e];
        // stable softplus: max(p,0) + log1p(exp(-|p|))
        const float sp = fmaxf(p, 0.f) + log1pf(expf(-fabsf(p)));
        v[e] = fmaf(nzv[e], sp, g[e]);
    }

    // top-2 of 8; strict '>' keeps the lowest index on ties, matching
    // jax.lax.top_k / torch.topk ordering.
    int i1 = 0; float m1 = v[0];
#pragma unroll
    for (int e = 1; e < RE; ++e)
        if (v[e] > m1) { m1 = v[e]; i1 = e; }
    int i2 = -1; float m2 = -INFINITY;
#pragma unroll
    for (int e = 0; e < RE; ++e)
        if (e != i1 && v[e] > m2) { m2 = v[e]; i2 = e; }

    const float e2 = expf(m2 - m1);
    const float inv = 1.f / (1.f + e2);
    const float p1s = inv;
    const float p2s = e2 * inv;

    float r[RE];
#pragma unroll
    for (int e = 0; e < RE; ++e)
        r[e] = (e == i1) ? p1s : ((e == i2) ? p2s : 0.f);

    float4* orow = reinterpret_cast<float4*>(out_router + (size_t)tok * RE);
    orow[0] = make_float4(r[0], r[1], r[2], r[3]);
    orow[1] = make_float4(r[4], r[5], r[6], r[7]);

    float2* erow = reinterpret_cast<float2*>(out_experts + (size_t)tok * 2);
    *erow = make_float2((float)i1, (float)i2);
}

extern "C" void kernel_launch(void* const* d_in, const int* in_sizes, int n_in,
                              void* d_out, int out_size, void* d_ws, size_t ws_size,
                              hipStream_t stream) {
    const float* x   = (const float*)d_in[0];
    const float* Wg  = (const float*)d_in[1];
    const float* bg  = (const float*)d_in[2];
    const float* Wn  = (const float*)d_in[3];
    const float* bn  = (const float*)d_in[4];
    const float* nz  = (const float*)d_in[5];
    const int T = in_sizes[0] / RD;              // 32768

    float* WT  = (float*)d_ws;                   // 128 KB
    float* pws = WT + (size_t)RD * NE16;         // KSL*T*16 floats = 4 MB

    float* out_router  = (float*)d_out;                // T*8 floats
    float* out_experts = out_router + (size_t)T * RE;  // T*2 floats (as f32)

    hipLaunchKernelGGL(transpose_w_kernel, dim3((RD * NE16) / 256), dim3(256),
                       0, stream, Wg, Wn, WT);

    const int NTB = T / TOKB;                    // 512
    hipLaunchKernelGGL(router_main_kernel, dim3(NTB * KSL), dim3(256), 0,
                       stream, x, WT, pws, T);

    hipLaunchKernelGGL(router_finalize_kernel, dim3(T / 256), dim3(256), 0,
                       stream, pws, bg, bn, nz, out_router, out_experts, T);
}